// Round 4
// baseline (86.623 us; speedup 1.0000x reference)
//
#include <hip/hip_runtime.h>
#include <math.h>

#define BB 32
#define NN 512
#define PP 130816            // N*(N-1)/2
#define KBLK 64              // blocks per row in pair kernel
#define TAILSUB (KBLK - 2)   // the sub-block that owns the d=256 tail

// ws float offsets
#define OFF_RS2 0            // float2 {r|NaN, s} [BB][NN] = 32768 floats
#define OFF_CF  32768        // coeffs: tau[6], w[6], gneg[10], gpos[10], pad, gB@32
#define OFF_SUM 32816        // rowsum[32]
#define OFF_CNT 32848        // rowcnt[32]

__device__ __forceinline__ float splus(float z) {
    return fmaxf(z, 0.0f) + __logf(1.0f + __expf(-fabsf(z)));
}

// np.linspace grids (float64 math, cast to f32 — matches numpy)
__device__ __constant__ float ST8[8] = {0.5f, 1.0f, 1.5f, 2.0f, 2.5f, 3.0f, 3.5f, 4.0f};
__device__ __constant__ float BT8[8] = {
    (float)(-2.0), (float)(-2.0 + 4.0/7.0), (float)(-2.0 + 8.0/7.0),
    (float)(-2.0 + 12.0/7.0), (float)(-2.0 + 16.0/7.0),
    (float)(-2.0 + 20.0/7.0), (float)(-2.0 + 24.0/7.0), 2.0f };
__device__ __constant__ float SW6[6] = {0.5f, (float)(0.5 + 3.5/5.0), (float)(0.5 + 7.0/5.0),
    (float)(0.5 + 10.5/5.0), (float)(0.5 + 14.0/5.0), 4.0f};
__device__ __constant__ float BW6[6] = {-2.0f, (float)(-2.0 + 4.0/5.0), (float)(-2.0 + 8.0/5.0),
    (float)(-2.0 + 12.0/5.0), (float)(-2.0 + 16.0/5.0), 2.0f};

// Chebyshev T_j -> monomial t^p conversion, row j col p
__device__ __constant__ float TC[10][10] = {
    {1,0,0,0,0,0,0,0,0,0},
    {0,1,0,0,0,0,0,0,0,0},
    {-1,0,2,0,0,0,0,0,0,0},
    {0,-3,0,4,0,0,0,0,0,0},
    {1,0,-8,0,8,0,0,0,0,0},
    {0,5,0,-20,0,16,0,0,0,0},
    {-1,0,18,0,-48,0,32,0,0,0},
    {0,-7,0,56,0,-112,0,64,0,0},
    {1,0,-32,0,160,0,-256,0,128,0},
    {0,9,0,-120,0,432,0,-576,0,256},
};

// blocks 0..31: row normalize (+NaN-mask fold into r). block 32: poly fits.
__global__ __launch_bounds__(256)
void prep_kernel(const float* __restrict__ pred, const float* __restrict__ targ,
                 const float* __restrict__ th_tau, const float* __restrict__ th_g,
                 const float* __restrict__ th_w, float* __restrict__ ws)
{
    const int bid = blockIdx.x, tid = threadIdx.x;
    if (bid < BB) {
        const int base = bid * NN;
        float x0 = pred[base + tid], x1 = pred[base + tid + 256];
        float t0 = targ[base + tid], t1 = targ[base + tid + 256];
        bool v0 = fabsf(t0 + 1.0f) > 1.00001e-5f;
        bool v1 = fabsf(t1 + 1.0f) > 1.00001e-5f;
        float m0 = v0 ? 1.0f : 0.0f, m1 = v1 ? 1.0f : 0.0f;
        float xs0 = x0 * m0, xs1 = x1 * m1;
        float lsum = xs0 + xs1;
        float lsq  = xs0 * xs0 + xs1 * xs1;
        float lcnt = m0 + m1;
        #pragma unroll
        for (int off = 32; off; off >>= 1) {
            lsum += __shfl_down(lsum, off);
            lsq  += __shfl_down(lsq,  off);
            lcnt += __shfl_down(lcnt, off);
        }
        __shared__ float red[3][4];
        const int lane = tid & 63, wv = tid >> 6;
        if (lane == 0) { red[0][wv] = lsum; red[1][wv] = lsq; red[2][wv] = lcnt; }
        __syncthreads();
        __shared__ float mean_s, rsig_s;
        if (tid == 0) {
            float S = 0.0f, Q = 0.0f, C = 0.0f;
            for (int i = 0; i < 4; i++) { S += red[0][i]; Q += red[1][i]; C += red[2][i]; }
            float denom = fmaxf(C, 1.0f);
            float mean = S / denom;
            float var = Q / denom - mean * mean;
            mean_s = mean;
            rsig_s = 1.0f / sqrtf(var + 1e-6f);
            ws[OFF_SUM + bid] = 0.0f;
            ws[OFF_CNT + bid] = 0.0f;
        }
        __syncthreads();
        const float qnan = __uint_as_float(0x7fc00000u);
        float2* RS2 = (float2*)(ws + OFF_RS2);
        RS2[base + tid]       = make_float2(v0 ? t0 : qnan, (xs0 - mean_s) * rsig_s);
        RS2[base + tid + 256] = make_float2(v1 ? t1 : qnan, (xs1 - mean_s) * rsig_s);
    } else {
        // ---- poly-fit block: wave w fits function w at 64 Chebyshev nodes ----
        // task 0: tau(adr) [0,1] deg5 | 1: w(adr) [0,1] deg5
        // task 2: g(m) [-16,0] deg9   | 3: g(m) [0,16] deg9
        const int wv = tid >> 6, lane = tid & 63;
        __shared__ float fbuf[4][64];
        __shared__ float cbuf[4][10];
        const float mids[4]  = {0.5f, 0.5f, -8.0f, 8.0f};
        const float halfs[4] = {0.5f, 0.5f,  8.0f, 8.0f};
        const int   ncs[4]   = {6, 6, 10, 10};
        const int   bases[4] = {0, 6, 12, 22};
        float u = __cosf((float)M_PI * ((float)lane + 0.5f) * (1.0f / 64.0f));
        float xv = fmaf(halfs[wv], u, mids[wv]);
        float f;
        if (wv == 0) {
            f = 0.0f;
            #pragma unroll
            for (int k = 0; k < 8; k++)
                f = fmaf(splus(fmaf(xv, ST8[k], BT8[k])), splus(th_tau[k]), f);
        } else if (wv == 1) {
            f = 0.001f;   // FLOOR folded in
            #pragma unroll
            for (int k = 0; k < 6; k++) {
                float z = fmaf(xv, SW6[k], BW6[k]);
                f = fmaf(1.0f / (1.0f + __expf(-z)), splus(th_w[k]), f);
            }
        } else {
            f = 0.0f;
            #pragma unroll
            for (int k = 0; k < 8; k++)
                f = fmaf(splus(fmaf(xv, ST8[k], BT8[k])), splus(th_g[k]), f);
        }
        fbuf[wv][lane] = f;
        __syncthreads();
        const int nc = ncs[wv];
        if (lane < nc) {
            // DCT projection: c_j = (2/64) sum_i f_i cos(j*pi*(i+0.5)/64), c_0 halved
            float c = 0.0f;
            for (int i = 0; i < 64; i++)
                c += fbuf[wv][i] * __cosf((float)M_PI * (float)lane * ((float)i + 0.5f) * (1.0f / 64.0f));
            c *= (lane == 0) ? (1.0f / 64.0f) : (2.0f / 64.0f);
            cbuf[wv][lane] = c;
        }
        __syncthreads();
        if (lane < nc) {
            float mono = 0.0f;
            for (int j = 0; j < nc; j++) mono += cbuf[wv][j] * TC[j][lane];
            ws[OFF_CF + bases[wv] + lane] = mono;
        }
        if (wv == 2 && lane == 0) {
            float gB = 0.0f;   // exact hi-side slope: softplus(z)->z for z>16
            #pragma unroll
            for (int k = 0; k < 8; k++) gB += splus(th_g[k]) * ST8[k];
            ws[OFF_CF + 32] = gB;
        }
    }
}

__global__ __launch_bounds__(256)
void pair_kernel(float* __restrict__ ws)
{
    const int b   = blockIdx.x & (BB - 1);
    const int sub = blockIdx.x >> 5;           // [0, KBLK)
    const int tid = threadIdx.x;
    __shared__ float2 sRS[NN];                 // {r|NaN, s}

    const float2* RS2 = (const float2*)(ws + OFF_RS2);
    sRS[tid]       = RS2[b * NN + tid];
    sRS[tid + 256] = RS2[b * NN + tid + 256];

    // polynomial coefficients (wave-uniform; tau/w -> SGPR, g -> VGPR for cndmask)
    float ct[6], cw[6], cn[10], cp[10];
    #pragma unroll
    for (int k = 0; k < 6; k++)  ct[k] = ws[OFF_CF + k];
    #pragma unroll
    for (int k = 0; k < 6; k++)  cw[k] = ws[OFF_CF + 6 + k];
    #pragma unroll
    for (int k = 0; k < 10; k++) cn[k] = ws[OFF_CF + 12 + k];
    #pragma unroll
    for (int k = 0; k < 10; k++) cp[k] = ws[OFF_CF + 22 + k];
    const float gB = ws[OFF_CF + 32];
    __syncthreads();

    float lsum = 0.0f, lcnt = 0.0f;

    auto do_pair = [&](float2 a, float2 q) {
        float dr  = a.x - q.x;
        float ds  = a.y - q.y;
        // t*ds via sign transfer (dr==0 / NaN cases dropped by keep below)
        float tds = __uint_as_float(__float_as_uint(ds) ^
                                    (__float_as_uint(dr) & 0x80000000u));
        float t1  = fmaf(fabsf(dr), 2.0f, -1.0f);          // tau/w domain var
        float tau = fmaf(ct[5], t1, ct[4]);
        tau = fmaf(tau, t1, ct[3]); tau = fmaf(tau, t1, ct[2]);
        tau = fmaf(tau, t1, ct[1]); tau = fmaf(tau, t1, ct[0]);
        float w = fmaf(cw[5], t1, cw[4]);
        w = fmaf(w, t1, cw[3]); w = fmaf(w, t1, cw[2]);
        w = fmaf(w, t1, cw[1]); w = fmaf(w, t1, cw[0]);
        float m  = tau - tds;
        float um = fminf(fmaxf(m, -16.0f), 16.0f);
        bool neg = m < 0.0f;
        float tg = fmaf(um, 0.125f, neg ? 1.0f : -1.0f);   // map to [-1,1] per piece
        float g = neg ? cn[9] : cp[9];
        #pragma unroll
        for (int k = 8; k >= 0; k--)
            g = fmaf(g, tg, neg ? cn[k] : cp[k]);
        g = fmaf(fmaxf(m - 16.0f, 0.0f), gB, g);           // exact linear hi-extension
        float p = g * w;
        bool keep = __builtin_islessgreater(dr, 0.0f);     // false for ties AND NaN(mask)
        lsum = keep ? (lsum + p) : lsum;                   // NaN p discarded by select
        lcnt = keep ? (lcnt + 1.0f) : lcnt;
    };

    // stride mapping: x constant per thread, d = d0 + KBLK/2 * it
    const int d0 = (sub >> 1) + 1;                         // [1, 32]
    const int x  = ((sub & 1) << 8) + tid;
    const float2 rsi = sRS[x];
    int j = (x + d0) & (NN - 1);
    const int nIter = (sub >= TAILSUB) ? (PP / (KBLK * 256) - 1) : (PP / (KBLK * 256));
    for (int it = 0; it < nIter; it++) {
        float2 rsj = sRS[j];
        do_pair(rsi, rsj);
        j = (j + 32) & (NN - 1);
    }
    if (sub == TAILSUB) {                                   // d=256 tail, x<256
        do_pair(sRS[tid], sRS[tid + 256]);
    }

    #pragma unroll
    for (int off = 32; off; off >>= 1) {
        lsum += __shfl_down(lsum, off);
        lcnt += __shfl_down(lcnt, off);
    }
    __shared__ float red[2][4];
    const int lane = tid & 63, wv = tid >> 6;
    if (lane == 0) { red[0][wv] = lsum; red[1][wv] = lcnt; }
    __syncthreads();
    if (tid == 0) {
        float S = red[0][0] + red[0][1] + red[0][2] + red[0][3];
        float C = red[1][0] + red[1][1] + red[1][2] + red[1][3];
        atomicAdd(ws + OFF_SUM + b, S);
        atomicAdd(ws + OFF_CNT + b, C);
    }
}

__global__ void final_kernel(const float* __restrict__ ws, float* __restrict__ out)
{
    const int tid = threadIdx.x;  // 64 threads, single wave
    float val = 0.0f, vld = 0.0f;
    if (tid < BB) {
        float c = ws[OFF_CNT + tid], s = ws[OFF_SUM + tid];
        float rl = s / fmaxf(c, 1.0f);
        float v  = (c > 0.0f) ? 1.0f : 0.0f;
        val = rl * v;
        vld = v;
    }
    #pragma unroll
    for (int off = 32; off; off >>= 1) {
        val += __shfl_down(val, off);
        vld += __shfl_down(vld, off);
    }
    if (tid == 0) out[0] = val / fmaxf(vld, 1.0f);
}

extern "C" void kernel_launch(void* const* d_in, const int* in_sizes, int n_in,
                              void* d_out, int out_size, void* d_ws, size_t ws_size,
                              hipStream_t stream) {
    const float* pred   = (const float*)d_in[0];
    const float* targ   = (const float*)d_in[1];
    const float* th_tau = (const float*)d_in[2];
    const float* th_g   = (const float*)d_in[3];
    const float* th_w   = (const float*)d_in[4];
    float* ws  = (float*)d_ws;
    float* out = (float*)d_out;

    prep_kernel<<<BB + 1, 256, 0, stream>>>(pred, targ, th_tau, th_g, th_w, ws);
    pair_kernel<<<BB * KBLK, 256, 0, stream>>>(ws);
    final_kernel<<<1, 64, 0, stream>>>(ws, out);
}

// Round 5
// 76.740 us; speedup vs baseline: 1.1288x; 1.1288x over previous
//
#include <hip/hip_runtime.h>
#include <math.h>

#define BB 32
#define NN 512

// ws float offsets
#define OFF_RS2 0            // float2 {r|NaN, s} [BB][NN] = 32768 floats
#define OFF_CF  32768        // coeffs: ct[6] cw[6] cE[10] cO[10], gB@32 (pad 40)
#define OFF_SUM 32808        // rowsum[32]
#define OFF_CNT 32840        // rowcnt[32]

__device__ __forceinline__ float splus(float z) {
    return fmaxf(z, 0.0f) + __logf(1.0f + __expf(-fabsf(z)));
}

// np.linspace grids (float64 math, cast to f32 — matches numpy)
__device__ __constant__ float ST8[8] = {0.5f, 1.0f, 1.5f, 2.0f, 2.5f, 3.0f, 3.5f, 4.0f};
__device__ __constant__ float BT8[8] = {
    (float)(-2.0), (float)(-2.0 + 4.0/7.0), (float)(-2.0 + 8.0/7.0),
    (float)(-2.0 + 12.0/7.0), (float)(-2.0 + 16.0/7.0),
    (float)(-2.0 + 20.0/7.0), (float)(-2.0 + 24.0/7.0), 2.0f };
__device__ __constant__ float SW6[6] = {0.5f, (float)(0.5 + 3.5/5.0), (float)(0.5 + 7.0/5.0),
    (float)(0.5 + 10.5/5.0), (float)(0.5 + 14.0/5.0), 4.0f};
__device__ __constant__ float BW6[6] = {-2.0f, (float)(-2.0 + 4.0/5.0), (float)(-2.0 + 8.0/5.0),
    (float)(-2.0 + 12.0/5.0), (float)(-2.0 + 16.0/5.0), 2.0f};

// Chebyshev T_j -> monomial t^p, row j col p
__device__ __constant__ float TC[10][10] = {
    {1,0,0,0,0,0,0,0,0,0},
    {0,1,0,0,0,0,0,0,0,0},
    {-1,0,2,0,0,0,0,0,0,0},
    {0,-3,0,4,0,0,0,0,0,0},
    {1,0,-8,0,8,0,0,0,0,0},
    {0,5,0,-20,0,16,0,0,0,0},
    {-1,0,18,0,-48,0,32,0,0,0},
    {0,-7,0,56,0,-112,0,64,0,0},
    {1,0,-32,0,160,0,-256,0,128,0},
    {0,9,0,-120,0,432,0,-576,0,256},
};

// blocks 0..31: row normalize (mask folded as NaN in r). block 32: poly fits.
__global__ __launch_bounds__(256)
void prep_kernel(const float* __restrict__ pred, const float* __restrict__ targ,
                 const float* __restrict__ th_tau, const float* __restrict__ th_g,
                 const float* __restrict__ th_w, float* __restrict__ ws)
{
    const int bid = blockIdx.x, tid = threadIdx.x;
    if (bid < BB) {
        const int base = bid * NN;
        float x0 = pred[base + tid], x1 = pred[base + tid + 256];
        float t0 = targ[base + tid], t1 = targ[base + tid + 256];
        bool v0 = fabsf(t0 + 1.0f) > 1.00001e-5f;
        bool v1 = fabsf(t1 + 1.0f) > 1.00001e-5f;
        float m0 = v0 ? 1.0f : 0.0f, m1 = v1 ? 1.0f : 0.0f;
        float xs0 = x0 * m0, xs1 = x1 * m1;
        float lsum = xs0 + xs1;
        float lsq  = xs0 * xs0 + xs1 * xs1;
        float lcnt = m0 + m1;
        #pragma unroll
        for (int off = 32; off; off >>= 1) {
            lsum += __shfl_down(lsum, off);
            lsq  += __shfl_down(lsq,  off);
            lcnt += __shfl_down(lcnt, off);
        }
        __shared__ float red[3][4];
        const int lane = tid & 63, wv = tid >> 6;
        if (lane == 0) { red[0][wv] = lsum; red[1][wv] = lsq; red[2][wv] = lcnt; }
        __syncthreads();
        __shared__ float mean_s, rsig_s;
        if (tid == 0) {
            float S = 0.0f, Q = 0.0f, C = 0.0f;
            for (int i = 0; i < 4; i++) { S += red[0][i]; Q += red[1][i]; C += red[2][i]; }
            float denom = fmaxf(C, 1.0f);
            float mean = S / denom;
            float var = Q / denom - mean * mean;
            mean_s = mean;
            rsig_s = 1.0f / sqrtf(var + 1e-6f);
            ws[OFF_SUM + bid] = 0.0f;
            ws[OFF_CNT + bid] = 0.0f;
        }
        __syncthreads();
        const float qnan = __uint_as_float(0x7fc00000u);
        float2* RS2 = (float2*)(ws + OFF_RS2);
        RS2[base + tid]       = make_float2(v0 ? t0 : qnan, (xs0 - mean_s) * rsig_s);
        RS2[base + tid + 256] = make_float2(v1 ? t1 : qnan, (xs1 - mean_s) * rsig_s);
    } else {
        // wave 0: tau(adr), [0,1], deg5 | wave 1: w(adr), [0,1], deg5
        // wave 2: E(u)=(g(u)+g(-u))/2, [0,16], deg9 | wave 3: O(u)=(g(u)-g(-u))/2
        const int wv = tid >> 6, lane = tid & 63;
        __shared__ float fbuf[4][64];
        __shared__ float cbuf[4][10];
        float u = __cosf((float)M_PI * ((float)lane + 0.5f) * (1.0f / 64.0f));
        float f;
        if (wv == 0) {
            float xv = fmaf(0.5f, u, 0.5f);
            f = 0.0f;
            #pragma unroll
            for (int k = 0; k < 8; k++)
                f = fmaf(splus(fmaf(xv, ST8[k], BT8[k])), splus(th_tau[k]), f);
        } else if (wv == 1) {
            float xv = fmaf(0.5f, u, 0.5f);
            f = 0.001f;   // FLOOR folded in
            #pragma unroll
            for (int k = 0; k < 6; k++) {
                float z = fmaf(xv, SW6[k], BW6[k]);
                f = fmaf(1.0f / (1.0f + __expf(-z)), splus(th_w[k]), f);
            }
        } else {
            float xv = fmaf(8.0f, u, 8.0f);           // u-node in [0,16]
            float gp = 0.0f, gn = 0.0f;
            #pragma unroll
            for (int k = 0; k < 8; k++) {
                float c = splus(th_g[k]);
                gp = fmaf(splus(fmaf( xv, ST8[k], BT8[k])), c, gp);
                gn = fmaf(splus(fmaf(-xv, ST8[k], BT8[k])), c, gn);
            }
            f = (wv == 2) ? 0.5f * (gp + gn) : 0.5f * (gp - gn);
        }
        fbuf[wv][lane] = f;
        __syncthreads();
        const int nc   = (wv < 2) ? 6 : 10;
        const int base = (wv == 0) ? 0 : (wv == 1) ? 6 : (wv == 2) ? 12 : 22;
        if (lane < nc) {
            float c = 0.0f;
            for (int i = 0; i < 64; i++)
                c += fbuf[wv][i] * __cosf((float)M_PI * (float)lane * ((float)i + 0.5f) * (1.0f / 64.0f));
            c *= (lane == 0) ? (1.0f / 64.0f) : (2.0f / 64.0f);
            cbuf[wv][lane] = c;
        }
        __syncthreads();
        if (lane < nc) {
            float mono = 0.0f;
            for (int j = 0; j < nc; j++) mono += cbuf[wv][j] * TC[j][lane];
            ws[OFF_CF + base + lane] = mono;
        }
        if (wv == 2 && lane == 0) {
            float gB = 0.0f;   // exact hi-side slope (softplus(z)->z, z>16)
            #pragma unroll
            for (int k = 0; k < 8; k++) gB += splus(th_g[k]) * ST8[k];
            ws[OFF_CF + 32] = gB;
        }
    }
}

__global__ __launch_bounds__(256)
void pair_kernel(const float2* __restrict__ RS2, const float* __restrict__ CF,
                 float* __restrict__ sums)
{
    const int b   = blockIdx.x & (BB - 1);   // row
    const int sub = blockIdx.x >> 5;         // d-octet: d = 8*sub+1 .. 8*sub+8
    const int tid = threadIdx.x;
    __shared__ float2 sRS[768];              // wrapped mirror: sRS[k] = row[k & 511]
    sRS[tid]       = RS2[b * NN + tid];
    sRS[tid + 256] = RS2[b * NN + tid + 256];
    sRS[tid + 512] = RS2[b * NN + tid];

    // coefficients: uniform-address loads -> SGPRs (CF is const __restrict__)
    float ct[6], cw[6], ce[10], co[10];
    #pragma unroll
    for (int k = 0; k < 6; k++)  ct[k] = CF[k];
    #pragma unroll
    for (int k = 0; k < 6; k++)  cw[k] = CF[6 + k];
    #pragma unroll
    for (int k = 0; k < 10; k++) ce[k] = CF[12 + k];
    #pragma unroll
    for (int k = 0; k < 10; k++) co[k] = CF[22 + k];
    const float gB = CF[32];
    __syncthreads();

    float lsum = 0.0f, lcnt = 0.0f;

    auto do_pair = [&](float2 a, float2 q, bool allow) {
        float dr  = a.x - q.x;
        float ds  = a.y - q.y;
        unsigned sgn = __float_as_uint(dr) & 0x80000000u;
        float tds = __uint_as_float(__float_as_uint(ds) ^ sgn);   // t*ds
        float t1  = fmaf(fabsf(dr), 2.0f, -1.0f);
        float tau = fmaf(ct[5], t1, ct[4]);
        tau = fmaf(tau, t1, ct[3]); tau = fmaf(tau, t1, ct[2]);
        tau = fmaf(tau, t1, ct[1]); tau = fmaf(tau, t1, ct[0]);
        float w = fmaf(cw[5], t1, cw[4]);
        w = fmaf(w, t1, cw[3]); w = fmaf(w, t1, cw[2]);
        w = fmaf(w, t1, cw[1]); w = fmaf(w, t1, cw[0]);
        float m  = tau - tds;
        float au = fminf(fabsf(m), 16.0f);
        float tg = fmaf(au, 0.125f, -1.0f);                       // [0,16] -> [-1,1]
        float E = ce[9], O = co[9];
        #pragma unroll
        for (int k = 8; k >= 0; k--) {
            E = fmaf(E, tg, ce[k]);
            O = fmaf(O, tg, co[k]);
        }
        unsigned msgn = __float_as_uint(m) & 0x80000000u;
        float g = E + __uint_as_float(__float_as_uint(O) ^ msgn); // E + sign(m)*O
        g = fmaf(fmaxf(m - 16.0f, 0.0f), gB, g);                  // exact hi extension
        float p = g * w;
        bool keep = __builtin_islessgreater(dr, 0.0f) && allow;   // ties & NaN-mask drop
        lsum = keep ? (lsum + p) : lsum;
        lcnt = keep ? (lcnt + 1.0f) : lcnt;
    };

    const int d0 = sub * 8 + 1;
    const float2 a0 = sRS[tid];
    const float2 a1 = sRS[tid + 256];
    const float2* pj0 = &sRS[tid + d0];
    const float2* pj1 = &sRS[tid + 256 + d0];
    const bool lastsub = (sub == 31);
    #pragma unroll
    for (int k = 0; k < 8; k++)
        do_pair(a0, pj0[k], true);
    #pragma unroll
    for (int k = 0; k < 7; k++)
        do_pair(a1, pj1[k], true);
    do_pair(a1, pj1[7], !lastsub);   // (x+256, d=256) duplicates (x, d=256): skip

    #pragma unroll
    for (int off = 32; off; off >>= 1) {
        lsum += __shfl_down(lsum, off);
        lcnt += __shfl_down(lcnt, off);
    }
    __shared__ float red[2][4];
    const int lane = tid & 63, wv = tid >> 6;
    if (lane == 0) { red[0][wv] = lsum; red[1][wv] = lcnt; }
    __syncthreads();
    if (tid == 0) {
        float S = red[0][0] + red[0][1] + red[0][2] + red[0][3];
        float C = red[1][0] + red[1][1] + red[1][2] + red[1][3];
        atomicAdd(sums + b, S);
        atomicAdd(sums + BB + b, C);
    }
}

__global__ void final_kernel(const float* __restrict__ sums, float* __restrict__ out)
{
    const int tid = threadIdx.x;  // 64 threads, single wave
    float val = 0.0f, vld = 0.0f;
    if (tid < BB) {
        float s = sums[tid], c = sums[BB + tid];
        float rl = s / fmaxf(c, 1.0f);
        float v  = (c > 0.0f) ? 1.0f : 0.0f;
        val = rl * v;
        vld = v;
    }
    #pragma unroll
    for (int off = 32; off; off >>= 1) {
        val += __shfl_down(val, off);
        vld += __shfl_down(vld, off);
    }
    if (tid == 0) out[0] = val / fmaxf(vld, 1.0f);
}

extern "C" void kernel_launch(void* const* d_in, const int* in_sizes, int n_in,
                              void* d_out, int out_size, void* d_ws, size_t ws_size,
                              hipStream_t stream) {
    const float* pred   = (const float*)d_in[0];
    const float* targ   = (const float*)d_in[1];
    const float* th_tau = (const float*)d_in[2];
    const float* th_g   = (const float*)d_in[3];
    const float* th_w   = (const float*)d_in[4];
    float* ws  = (float*)d_ws;
    float* out = (float*)d_out;

    prep_kernel<<<BB + 1, 256, 0, stream>>>(pred, targ, th_tau, th_g, th_w, ws);
    pair_kernel<<<BB * 32, 256, 0, stream>>>((const float2*)(ws + OFF_RS2),
                                             ws + OFF_CF, ws + OFF_SUM);
    final_kernel<<<1, 64, 0, stream>>>(ws + OFF_SUM, out);
}

// Round 6
// 72.873 us; speedup vs baseline: 1.1887x; 1.0531x over previous
//
#include <hip/hip_runtime.h>
#include <math.h>

#define BB 32
#define NN 512
#define NSUB 16              // d-chunks per row; each owns 16 distances

__device__ __forceinline__ float splus(float z) {
    return fmaxf(z, 0.0f) + __logf(1.0f + __expf(-fabsf(z)));
}

// np.linspace grids (float64 math, cast to f32 — matches numpy)
__device__ __constant__ float ST8[8] = {0.5f, 1.0f, 1.5f, 2.0f, 2.5f, 3.0f, 3.5f, 4.0f};
__device__ __constant__ float BT8[8] = {
    (float)(-2.0), (float)(-2.0 + 4.0/7.0), (float)(-2.0 + 8.0/7.0),
    (float)(-2.0 + 12.0/7.0), (float)(-2.0 + 16.0/7.0),
    (float)(-2.0 + 20.0/7.0), (float)(-2.0 + 24.0/7.0), 2.0f };
__device__ __constant__ float SW6[6] = {0.5f, (float)(0.5 + 3.5/5.0), (float)(0.5 + 7.0/5.0),
    (float)(0.5 + 10.5/5.0), (float)(0.5 + 14.0/5.0), 4.0f};
__device__ __constant__ float BW6[6] = {-2.0f, (float)(-2.0 + 4.0/5.0), (float)(-2.0 + 8.0/5.0),
    (float)(-2.0 + 12.0/5.0), (float)(-2.0 + 16.0/5.0), 2.0f};

// Chebyshev T_j -> monomial t^p, row j col p
__device__ __constant__ float TC[10][10] = {
    {1,0,0,0,0,0,0,0,0,0},
    {0,1,0,0,0,0,0,0,0,0},
    {-1,0,2,0,0,0,0,0,0,0},
    {0,-3,0,4,0,0,0,0,0,0},
    {1,0,-8,0,8,0,0,0,0,0},
    {0,5,0,-20,0,16,0,0,0,0},
    {-1,0,18,0,-48,0,32,0,0,0},
    {0,-7,0,56,0,-112,0,64,0,0},
    {1,0,-32,0,160,0,-256,0,128,0},
    {0,9,0,-120,0,432,0,-576,0,256},
};

// One kernel does everything except the last 512->1 combine.
// Block = (row b, d-chunk sub). Redundant per-block: row normalization + poly
// fits (parallel across otherwise-idle CUs; removes a launch + global round-trip).
__global__ __launch_bounds__(256)
void fused_kernel(const float* __restrict__ pred, const float* __restrict__ targ,
                  const float* __restrict__ th_tau, const float* __restrict__ th_g,
                  const float* __restrict__ th_w, float2* __restrict__ part)
{
    const int b   = blockIdx.x & (BB - 1);
    const int sub = blockIdx.x >> 5;           // [0, NSUB)
    const int tid = threadIdx.x;
    const int lane = tid & 63, wv = tid >> 6;

    __shared__ float2 sRS[768];                // wrapped mirror {r|NaN, s}
    __shared__ float  red[3][4];
    __shared__ float  fbuf[4][64];
    __shared__ float  cbuf[4][10];
    __shared__ float  cf[40];                  // ct[6] cw[6] cE[10] cO[10], gB@32
    __shared__ float  mean_s, rsig_s;

    // ---- phase 1: row load + masked moments; fit node evals (independent) ----
    const int base = b * NN;
    float x0 = pred[base + tid], x1 = pred[base + tid + 256];
    float t0 = targ[base + tid], t1 = targ[base + tid + 256];
    bool v0 = fabsf(t0 + 1.0f) > 1.00001e-5f;
    bool v1 = fabsf(t1 + 1.0f) > 1.00001e-5f;
    float xs0 = v0 ? x0 : 0.0f, xs1 = v1 ? x1 : 0.0f;
    {
        float lsum = xs0 + xs1;
        float lsq  = xs0 * xs0 + xs1 * xs1;
        float lcnt = (v0 ? 1.0f : 0.0f) + (v1 ? 1.0f : 0.0f);
        #pragma unroll
        for (int off = 32; off; off >>= 1) {
            lsum += __shfl_down(lsum, off);
            lsq  += __shfl_down(lsq,  off);
            lcnt += __shfl_down(lcnt, off);
        }
        if (lane == 0) { red[0][wv] = lsum; red[1][wv] = lsq; red[2][wv] = lcnt; }
    }
    {   // fit node eval: wave 0 tau | 1 w | 2 E=(g(u)+g(-u))/2 | 3 O=(g(u)-g(-u))/2
        float u = __cosf((float)M_PI * ((float)lane + 0.5f) * (1.0f / 64.0f));
        float f;
        if (wv == 0) {
            float xv = fmaf(0.5f, u, 0.5f);
            f = 0.0f;
            #pragma unroll
            for (int k = 0; k < 8; k++)
                f = fmaf(splus(fmaf(xv, ST8[k], BT8[k])), splus(th_tau[k]), f);
        } else if (wv == 1) {
            float xv = fmaf(0.5f, u, 0.5f);
            f = 0.001f;   // FLOOR folded in
            #pragma unroll
            for (int k = 0; k < 6; k++) {
                float z = fmaf(xv, SW6[k], BW6[k]);
                f = fmaf(1.0f / (1.0f + __expf(-z)), splus(th_w[k]), f);
            }
        } else {
            float xv = fmaf(8.0f, u, 8.0f);    // u-node in [0,16]
            float gp = 0.0f, gn = 0.0f;
            #pragma unroll
            for (int k = 0; k < 8; k++) {
                float c = splus(th_g[k]);
                gp = fmaf(splus(fmaf( xv, ST8[k], BT8[k])), c, gp);
                gn = fmaf(splus(fmaf(-xv, ST8[k], BT8[k])), c, gn);
            }
            f = (wv == 2) ? 0.5f * (gp + gn) : 0.5f * (gp - gn);
        }
        fbuf[wv][lane] = f;
    }
    __syncthreads();

    // ---- phase 2: moments combine (lane0/wave0) + DCT/mono (10 lanes/wave) ----
    if (tid == 0) {
        float S = 0.0f, Q = 0.0f, C = 0.0f;
        for (int i = 0; i < 4; i++) { S += red[0][i]; Q += red[1][i]; C += red[2][i]; }
        float denom = fmaxf(C, 1.0f);
        float mean = S / denom;
        float var = Q / denom - mean * mean;
        mean_s = mean;
        rsig_s = 1.0f / sqrtf(var + 1e-6f);
    }
    {
        const int nc    = (wv < 2) ? 6 : 10;
        const int cbase = (wv == 0) ? 0 : (wv == 1) ? 6 : (wv == 2) ? 12 : 22;
        if (lane < nc) {
            float c = 0.0f;
            for (int i = 0; i < 64; i++)
                c += fbuf[wv][i] * __cosf((float)M_PI * (float)lane * ((float)i + 0.5f) * (1.0f / 64.0f));
            c *= (lane == 0) ? (1.0f / 64.0f) : (2.0f / 64.0f);
            cbuf[wv][lane] = c;
            float mono = 0.0f;
            for (int j = 0; j < nc; j++) mono += cbuf[wv][j] * TC[j][lane];
            cf[cbase + lane] = mono;   // NB: cbuf[wv][j] for j>lane written by same wave
        }
        if (wv == 2 && lane == 0) {
            float gB = 0.0f;           // exact hi-side slope (softplus(z)->z, z>16)
            #pragma unroll
            for (int k = 0; k < 8; k++) gB += splus(th_g[k]) * ST8[k];
            cf[32] = gB;
        }
    }
    __syncthreads();

    // ---- phase 3: publish row to LDS; pull coeffs to registers ----
    const float qnan = __uint_as_float(0x7fc00000u);
    float2 e0 = make_float2(v0 ? t0 : qnan, (xs0 - mean_s) * rsig_s);
    float2 e1 = make_float2(v1 ? t1 : qnan, (xs1 - mean_s) * rsig_s);
    sRS[tid] = e0; sRS[tid + 256] = e1; sRS[tid + 512] = e0;
    float ct[6], cw[6], ce[10], co[10];
    #pragma unroll
    for (int k = 0; k < 6; k++)  ct[k] = cf[k];
    #pragma unroll
    for (int k = 0; k < 6; k++)  cw[k] = cf[6 + k];
    #pragma unroll
    for (int k = 0; k < 10; k++) ce[k] = cf[12 + k];
    #pragma unroll
    for (int k = 0; k < 10; k++) co[k] = cf[22 + k];
    const float gB = cf[32];
    __syncthreads();

    // ---- phase 4: pairs ----
    float lsum = 0.0f, lcnt = 0.0f;
    auto do_pair = [&](float2 a, float2 q, bool allow) {
        float dr  = a.x - q.x;
        float ds  = a.y - q.y;
        unsigned sgn = __float_as_uint(dr) & 0x80000000u;
        float tds = __uint_as_float(__float_as_uint(ds) ^ sgn);   // t*ds
        float t1v = fmaf(fabsf(dr), 2.0f, -1.0f);
        float tau = fmaf(ct[5], t1v, ct[4]);
        tau = fmaf(tau, t1v, ct[3]); tau = fmaf(tau, t1v, ct[2]);
        tau = fmaf(tau, t1v, ct[1]); tau = fmaf(tau, t1v, ct[0]);
        float w = fmaf(cw[5], t1v, cw[4]);
        w = fmaf(w, t1v, cw[3]); w = fmaf(w, t1v, cw[2]);
        w = fmaf(w, t1v, cw[1]); w = fmaf(w, t1v, cw[0]);
        float m  = tau - tds;
        float au = fminf(fabsf(m), 16.0f);
        float tg = fmaf(au, 0.125f, -1.0f);                       // [0,16] -> [-1,1]
        float E = ce[9], O = co[9];
        #pragma unroll
        for (int k = 8; k >= 0; k--) {
            E = fmaf(E, tg, ce[k]);
            O = fmaf(O, tg, co[k]);
        }
        unsigned msgn = __float_as_uint(m) & 0x80000000u;
        float g = E + __uint_as_float(__float_as_uint(O) ^ msgn); // E + sign(m)*O
        g = fmaf(fmaxf(m - 16.0f, 0.0f), gB, g);                  // exact hi extension
        float p = g * w;
        bool keep = __builtin_islessgreater(dr, 0.0f) && allow;   // ties/NaN drop
        lsum = keep ? (lsum + p) : lsum;
        lcnt = keep ? (lcnt + 1.0f) : lcnt;
    };

    const int d0 = sub * 16 + 1;               // this block: d = d0 .. d0+15
    const float2 a0 = sRS[tid];
    const float2 a1 = sRS[tid + 256];
    const float2* p0 = &sRS[tid + d0];
    const float2* p1 = &sRS[tid + 256 + d0];
    #pragma unroll
    for (int k = 0; k < 16; k++) do_pair(a0, p0[k], true);
    #pragma unroll
    for (int k = 0; k < 15; k++) do_pair(a1, p1[k], true);
    do_pair(a1, p1[15], sub != NSUB - 1);      // (x+256,d=256) dups (x,d=256): skip

    // ---- phase 5: block reduce, private partial slot (no atomics, no zeroing) ----
    #pragma unroll
    for (int off = 32; off; off >>= 1) {
        lsum += __shfl_down(lsum, off);
        lcnt += __shfl_down(lcnt, off);
    }
    if (lane == 0) { red[0][wv] = lsum; red[1][wv] = lcnt; }
    __syncthreads();
    if (tid == 0) {
        float S = red[0][0] + red[0][1] + red[0][2] + red[0][3];
        float C = red[1][0] + red[1][1] + red[1][2] + red[1][3];
        part[blockIdx.x] = make_float2(S, C);
    }
}

__global__ __launch_bounds__(512)
void final_kernel(const float2* __restrict__ part, float* __restrict__ out)
{
    const int tid = threadIdx.x;               // 512 threads, one per partial
    __shared__ float rs[BB], rc[BB];
    if (tid < BB) { rs[tid] = 0.0f; rc[tid] = 0.0f; }
    __syncthreads();
    float2 p = part[tid];
    atomicAdd(&rs[tid & (BB - 1)], p.x);
    atomicAdd(&rc[tid & (BB - 1)], p.y);
    __syncthreads();
    if (tid < 64) {
        float val = 0.0f, vld = 0.0f;
        if (tid < BB) {
            float c = rc[tid], s = rs[tid];
            float rl = s / fmaxf(c, 1.0f);
            float v  = (c > 0.0f) ? 1.0f : 0.0f;
            val = rl * v;
            vld = v;
        }
        #pragma unroll
        for (int off = 32; off; off >>= 1) {
            val += __shfl_down(val, off);
            vld += __shfl_down(vld, off);
        }
        if (tid == 0) out[0] = val / fmaxf(vld, 1.0f);
    }
}

extern "C" void kernel_launch(void* const* d_in, const int* in_sizes, int n_in,
                              void* d_out, int out_size, void* d_ws, size_t ws_size,
                              hipStream_t stream) {
    const float* pred   = (const float*)d_in[0];
    const float* targ   = (const float*)d_in[1];
    const float* th_tau = (const float*)d_in[2];
    const float* th_g   = (const float*)d_in[3];
    const float* th_w   = (const float*)d_in[4];
    float2* part = (float2*)d_ws;              // 512 float2 partials
    float* out   = (float*)d_out;

    fused_kernel<<<BB * NSUB, 256, 0, stream>>>(pred, targ, th_tau, th_g, th_w, part);
    final_kernel<<<1, 512, 0, stream>>>(part, out);
}